// Round 3
// baseline (670.348 us; speedup 1.0000x reference)
//
#include <hip/hip_runtime.h>
#include <math.h>

#define B 8192
#define D 512
#define NH 4
#define M 128
#define W 64
#define HW 256   // NH * W
#define RPB 8    // batch rows per block
#define EPS 1e-6f

// ---------------------------------------------------------------------------
// Fully fused: key GEMM + beta + cosine-sim + softmax in one kernel.
// Grid 1024 x 256; block owns batch rows [i0, i0+8).
// Phase 1: thread j owns key column j for all 8 rows (Wk coalesced, hidden
//          wave-uniform -> scalar loads). key -> LDS; u2 via wave butterfly
//          (wave w holds exactly head w's 64 columns); beta via repartition.
// Phase 2: 4 sub-iters; half-block (128 thr) per batch row; thread owns one
//          memory row (16 x float4 contiguous); softmax = wave butterfly +
//          2-wave LDS combine per half.
// ---------------------------------------------------------------------------
__global__ __launch_bounds__(256, 4) void fused_dynhead(
    const float* __restrict__ hid, const float* __restrict__ mem,
    const float* __restrict__ Wk,  const float* __restrict__ bk,
    const float* __restrict__ Wb,  const float* __restrict__ bb,
    float* __restrict__ out) {

    const int j  = threadIdx.x;
    const int i0 = blockIdx.x * RPB;

    __shared__ float ksh[RPB][HW];
    __shared__ float u2sh[RPB][NH];
    __shared__ float bsh[RPB][NH];
    __shared__ float redm[2][2][NH];
    __shared__ float reds[2][2][NH];

    // ---------------- phase 1: key GEMM ----------------
    const float* hbase = hid + (size_t)i0 * D;
    float acc[RPB];
#pragma unroll
    for (int ii = 0; ii < RPB; ++ii) acc[ii] = 0.f;

    for (int d = 0; d < D; ++d) {
        const float w = Wk[(size_t)d * HW + j];
#pragma unroll
        for (int ii = 0; ii < RPB; ++ii)
            acc[ii] = fmaf(hbase[(size_t)ii * D + d], w, acc[ii]);
    }

    const float bj   = bk[j];
    const int   wv   = j >> 6;   // wave id == head id for u2 reduction
    const int   lane = j & 63;
#pragma unroll
    for (int ii = 0; ii < RPB; ++ii) {
        const float k = tanhf(acc[ii] + bj);
        ksh[ii][j] = k;
        float s = k * k;
#pragma unroll
        for (int off = 1; off < 64; off <<= 1)
            s += __shfl_xor(s, off, 64);
        if (lane == 0) u2sh[ii][wv] = s + EPS;
    }

    // ---------------- fused beta ----------------
    {
        const int ii = j >> 5;        // row 0..7
        const int h  = (j >> 3) & 3;  // head
        const int q  = j & 7;         // eighth of D
        const float* hrow = hbase + (size_t)ii * D + q * 64;
        const float* wcol = Wb + (size_t)(q * 64) * NH + h;
        float a2 = 0.f;
#pragma unroll 4
        for (int d = 0; d < 64; ++d)
            a2 = fmaf(hrow[d], wcol[(size_t)d * NH], a2);
        a2 += __shfl_xor(a2, 1, 64);
        a2 += __shfl_xor(a2, 2, 64);
        a2 += __shfl_xor(a2, 4, 64);
        if (q == 0) {
            const float x = a2 + bb[h];
            bsh[ii][h] = fmaxf(x, 0.f) + log1pf(expf(-fabsf(x)));  // stable softplus
        }
    }
    __syncthreads();

    // ---------------- phase 2: cosine sim + softmax ----------------
    const int half = j >> 7;        // which batch row of the pair
    const int hwv  = (j >> 6) & 1;  // wave within the half
    const int mrow = j & 127;

#pragma unroll
    for (int s = 0; s < 4; ++s) {
        const int row = s * 2 + half;
        const float4* rp =
            (const float4*)(mem + (size_t)(i0 + row) * (M * W) + (size_t)mrow * W);

        float v2 = 0.f;
        float nh[NH] = {0.f, 0.f, 0.f, 0.f};
#pragma unroll
        for (int c = 0; c < 16; ++c) {
            const float4 x = rp[c];
            v2 = fmaf(x.x, x.x, fmaf(x.y, x.y, fmaf(x.z, x.z, fmaf(x.w, x.w, v2))));
#pragma unroll
            for (int h = 0; h < NH; ++h) {
                const float4 kk = *(const float4*)&ksh[row][h * W + c * 4];
                nh[h] = fmaf(x.x, kk.x, fmaf(x.y, kk.y, fmaf(x.z, kk.z, fmaf(x.w, kk.w, nh[h]))));
            }
        }
        v2 += EPS;

        float logit[NH], e[NH];
#pragma unroll
        for (int h = 0; h < NH; ++h) {
            const float den = sqrtf(u2sh[row][h] * v2);
            logit[h] = (nh[h] / (den + EPS)) * bsh[row][h];
        }

#pragma unroll
        for (int h = 0; h < NH; ++h) {
            float m_ = logit[h];
#pragma unroll
            for (int off = 1; off < 64; off <<= 1)
                m_ = fmaxf(m_, __shfl_xor(m_, off, 64));
            if (lane == 0) redm[half][hwv][h] = m_;
        }
        __syncthreads();

#pragma unroll
        for (int h = 0; h < NH; ++h)
            e[h] = expf(logit[h] - fmaxf(redm[half][0][h], redm[half][1][h]));

#pragma unroll
        for (int h = 0; h < NH; ++h) {
            float s_ = e[h];
#pragma unroll
            for (int off = 1; off < 64; off <<= 1)
                s_ += __shfl_xor(s_, off, 64);
            if (lane == 0) reds[half][hwv][h] = s_;
        }
        __syncthreads();

#pragma unroll
        for (int h = 0; h < NH; ++h) {
            const float tot = reds[half][0][h] + reds[half][1][h];
            out[(size_t)(i0 + row) * (NH * M) + (size_t)h * M + mrow] = e[h] / tot;
        }
        __syncthreads();  // protect redm/reds before next sub-iteration
    }
}

// ---------------------------------------------------------------------------
extern "C" void kernel_launch(void* const* d_in, const int* in_sizes, int n_in,
                              void* d_out, int out_size, void* d_ws, size_t ws_size,
                              hipStream_t stream) {
    const float* hid = (const float*)d_in[0];  // [B, D]
    const float* mem = (const float*)d_in[1];  // [B, M, W]
    const float* Wk  = (const float*)d_in[2];  // [D, HW]
    const float* bk  = (const float*)d_in[3];  // [HW]
    const float* Wb  = (const float*)d_in[4];  // [D, NH]
    const float* bb  = (const float*)d_in[5];  // [NH]
    float* out = (float*)d_out;                // [B, NH, M]

    fused_dynhead<<<B / RPB, 256, 0, stream>>>(hid, mem, Wk, bk, Wb, bb, out);
}

// Round 4
// 640.669 us; speedup vs baseline: 1.0463x; 1.0463x over previous
//
#include <hip/hip_runtime.h>
#include <math.h>

#define B 8192
#define D 512
#define NH 4
#define M 128
#define W 64
#define HW 256   // NH * W
#define RPB 8    // batch rows per block
#define EPS 1e-6f

// ---------------------------------------------------------------------------
// Fully fused: key GEMM + beta + cosine-sim + softmax in one kernel.
// Grid 1024 x 256; block owns batch rows [i0, i0+8).
// NOTE: no min-waves clamp in __launch_bounds__ — R3's (256,4) forced a
// 64-VGPR budget and spilled ~600 MB of scratch traffic per call.
// ---------------------------------------------------------------------------
__global__ __launch_bounds__(256) void fused_dynhead(
    const float* __restrict__ hid, const float* __restrict__ mem,
    const float* __restrict__ Wk,  const float* __restrict__ bk,
    const float* __restrict__ Wb,  const float* __restrict__ bb,
    float* __restrict__ out) {

    const int j  = threadIdx.x;
    const int i0 = blockIdx.x * RPB;

    __shared__ float ksh[RPB][HW];
    __shared__ float u2sh[RPB][NH];
    __shared__ float bsh[RPB][NH];
    __shared__ float redm[2][2][NH];
    __shared__ float reds[2][2][NH];

    // ---------------- phase 1: key GEMM ----------------
    const float* hbase = hid + (size_t)i0 * D;
    float acc[RPB];
#pragma unroll
    for (int ii = 0; ii < RPB; ++ii) acc[ii] = 0.f;

#pragma unroll 4
    for (int d = 0; d < D; ++d) {
        const float w = Wk[(size_t)d * HW + j];
#pragma unroll
        for (int ii = 0; ii < RPB; ++ii)
            acc[ii] = fmaf(hbase[(size_t)ii * D + d], w, acc[ii]);
    }

    const float bj   = bk[j];
    const int   wv   = j >> 6;   // wave id == head id for u2 reduction
    const int   lane = j & 63;
#pragma unroll
    for (int ii = 0; ii < RPB; ++ii) {
        const float k = tanhf(acc[ii] + bj);
        ksh[ii][j] = k;
        float s = k * k;
#pragma unroll
        for (int off = 1; off < 64; off <<= 1)
            s += __shfl_xor(s, off, 64);
        if (lane == 0) u2sh[ii][wv] = s + EPS;
    }

    // ---------------- fused beta ----------------
    {
        const int ii = j >> 5;        // row 0..7
        const int h  = (j >> 3) & 3;  // head
        const int q  = j & 7;         // eighth of D
        const float* hrow = hbase + (size_t)ii * D + q * 64;
        const float* wcol = Wb + (size_t)(q * 64) * NH + h;
        float a2 = 0.f;
#pragma unroll 4
        for (int d = 0; d < 64; ++d)
            a2 = fmaf(hrow[d], wcol[(size_t)d * NH], a2);
        a2 += __shfl_xor(a2, 1, 64);
        a2 += __shfl_xor(a2, 2, 64);
        a2 += __shfl_xor(a2, 4, 64);
        if (q == 0) {
            const float x = a2 + bb[h];
            bsh[ii][h] = fmaxf(x, 0.f) + log1pf(expf(-fabsf(x)));  // stable softplus
        }
    }
    __syncthreads();

    // ---------------- phase 2: cosine sim + softmax ----------------
    const int half = j >> 7;        // which batch row of the pair
    const int hwv  = (j >> 6) & 1;  // wave within the half
    const int mrow = j & 127;

#pragma unroll
    for (int s = 0; s < 4; ++s) {
        const int row = s * 2 + half;
        const float4* rp =
            (const float4*)(mem + (size_t)(i0 + row) * (M * W) + (size_t)mrow * W);

        float v2 = 0.f;
        float nh[NH] = {0.f, 0.f, 0.f, 0.f};
#pragma unroll
        for (int c = 0; c < 16; ++c) {
            const float4 x = rp[c];
            v2 = fmaf(x.x, x.x, fmaf(x.y, x.y, fmaf(x.z, x.z, fmaf(x.w, x.w, v2))));
#pragma unroll
            for (int h = 0; h < NH; ++h) {
                const float4 kk = *(const float4*)&ksh[row][h * W + c * 4];
                nh[h] = fmaf(x.x, kk.x, fmaf(x.y, kk.y, fmaf(x.z, kk.z, fmaf(x.w, kk.w, nh[h]))));
            }
        }
        v2 += EPS;

        float logit[NH], e[NH];
#pragma unroll
        for (int h = 0; h < NH; ++h) {
            const float den = sqrtf(u2sh[row][h] * v2);
            logit[h] = (nh[h] / (den + EPS)) * bsh[row][h];
        }

#pragma unroll
        for (int h = 0; h < NH; ++h) {
            float m_ = logit[h];
#pragma unroll
            for (int off = 1; off < 64; off <<= 1)
                m_ = fmaxf(m_, __shfl_xor(m_, off, 64));
            if (lane == 0) redm[half][hwv][h] = m_;
        }
        __syncthreads();

#pragma unroll
        for (int h = 0; h < NH; ++h)
            e[h] = expf(logit[h] - fmaxf(redm[half][0][h], redm[half][1][h]));

#pragma unroll
        for (int h = 0; h < NH; ++h) {
            float s_ = e[h];
#pragma unroll
            for (int off = 1; off < 64; off <<= 1)
                s_ += __shfl_xor(s_, off, 64);
            if (lane == 0) reds[half][hwv][h] = s_;
        }
        __syncthreads();

#pragma unroll
        for (int h = 0; h < NH; ++h) {
            const float tot = reds[half][0][h] + reds[half][1][h];
            out[(size_t)(i0 + row) * (NH * M) + (size_t)h * M + mrow] = e[h] / tot;
        }
        __syncthreads();  // protect redm/reds before next sub-iteration
    }
}

// ---------------------------------------------------------------------------
extern "C" void kernel_launch(void* const* d_in, const int* in_sizes, int n_in,
                              void* d_out, int out_size, void* d_ws, size_t ws_size,
                              hipStream_t stream) {
    const float* hid = (const float*)d_in[0];  // [B, D]
    const float* mem = (const float*)d_in[1];  // [B, M, W]
    const float* Wk  = (const float*)d_in[2];  // [D, HW]
    const float* bk  = (const float*)d_in[3];  // [HW]
    const float* Wb  = (const float*)d_in[4];  // [D, NH]
    const float* bb  = (const float*)d_in[5];  // [NH]
    float* out = (float*)d_out;                // [B, NH, M]

    fused_dynhead<<<B / RPB, 256, 0, stream>>>(hid, mem, Wk, bk, Wb, bb, out);
}